// Round 2
// baseline (13257.231 us; speedup 1.0000x reference)
//
#include <hip/hip_runtime.h>
#include <hip/hip_fp16.h>

typedef __attribute__((ext_vector_type(2))) _Float16 half2v;
typedef __attribute__((ext_vector_type(2))) __fp16   fp16x2;

#define NB   64
#define SEQ  512
#define EDIM 512

__device__ inline unsigned int pack2f16(float a, float b) {
    fp16x2 p = __builtin_amdgcn_cvt_pkrtz(a, b);
    return __builtin_bit_cast(unsigned int, p);
}

__device__ inline float fdot2u(unsigned int a, unsigned int b, float acc) {
#if __has_builtin(__builtin_amdgcn_fdot2)
    return __builtin_amdgcn_fdot2(__builtin_bit_cast(half2v, a),
                                  __builtin_bit_cast(half2v, b), acc, false);
#else
    half2v ha = __builtin_bit_cast(half2v, a);
    half2v hb = __builtin_bit_cast(half2v, b);
    return acc + (float)ha[0] * (float)hb[0] + (float)ha[1] * (float)hb[1];
#endif
}

__device__ inline float fsigmoid(float x) { return 1.f / (1.f + __expf(-x)); }
__device__ inline float ftanhf(float x) {
    float e = __expf(-2.f * fabsf(x));
    float t = (1.f - e) / (1.f + e);
    return copysignf(t, x);
}

// Pack Wq[512x512], Wx[512x1536], Wh[512x1536] (f32, row-major, K-major rows)
// into f16 pairs along K, vectorized as uint4 = 8 K-values per column.
// Layout: [K/8][C] uint4.  ws: Wq_p (32768), Wx_p (98304), Wh_p (98304).
__global__ __launch_bounds__(256)
void pack_weights(const float* __restrict__ Wq,
                  const float* __restrict__ Wx,
                  const float* __restrict__ Wh,
                  uint4* __restrict__ ws) {
    int tid = blockIdx.x * blockDim.x + threadIdx.x;  // 0 .. 229375
    const float* src; uint4* dst; int C, idx;
    if (tid < 64 * 512)              { src = Wq; dst = ws;                     C = 512;  idx = tid; }
    else if (tid < 64 * 512 + 64 * 1536) { src = Wx; dst = ws + 64 * 512;      C = 1536; idx = tid - 64 * 512; }
    else                             { src = Wh; dst = ws + 64 * 512 + 64 * 1536; C = 1536; idx = tid - (64 * 512 + 64 * 1536); }
    int m4 = idx / C;
    int c  = idx - m4 * C;
    const float* s = src + (size_t)(m4 * 8) * C + c;
    uint4 o;
    o.x = pack2f16(s[0 * (size_t)C], s[1 * (size_t)C]);
    o.y = pack2f16(s[2 * (size_t)C], s[3 * (size_t)C]);
    o.z = pack2f16(s[4 * (size_t)C], s[5 * (size_t)C]);
    o.w = pack2f16(s[6 * (size_t)C], s[7 * (size_t)C]);
    dst[idx] = o;
}

// One block per batch element. 512 threads = 8 waves; wave n = attention head n;
// thread e owns output column e of q, columns {e, e+512, e+1024} of gh/gx, and h[e].
__global__ __launch_bounds__(512)
void gru_scan(const int* __restrict__ xtok,
              const float* __restrict__ emb,
              const uint4* __restrict__ wsp,
              const float* __restrict__ bx,
              const float* __restrict__ bh,
              const float* __restrict__ W1,
              const float* __restrict__ b1,
              const float* __restrict__ W2,
              const float* __restrict__ b2,
              float* __restrict__ out) {
    const int b    = blockIdx.x;
    const int tid  = threadIdx.x;
    const int lane = tid & 63;

    const uint4* Wq_p = wsp;
    const uint4* Wx_p = wsp + 64 * 512;
    const uint4* Wh_p = wsp + 64 * 512 + 64 * 1536;

    __shared__ float win[3][512];      // rolling n-gram window (f32 embeddings)
    __shared__ uint4 h_pk4[64];        // h packed f16 pairs (512 vals)
    __shared__ uint4 c_pk4[64];        // ctx packed f16 pairs
    unsigned int* h_pku = (unsigned int*)h_pk4;
    unsigned int* c_pku = (unsigned int*)c_pk4;

    win[0][tid] = 0.f; win[1][tid] = 0.f; win[2][tid] = 0.f;
    if (tid < 256) h_pku[tid] = 0u;

    const float bx0 = bx[tid], bx1 = bx[tid + 512], bx2 = bx[tid + 1024];
    const float bh0 = bh[tid], bh1 = bh[tid + 512], bh2 = bh[tid + 1024];
    float hcur = 0.f;      // h[b][tid]
    float pooled = 0.f;    // sum over t of h
    const int* xrow = xtok + b * SEQ;
    __syncthreads();

    for (int t = 0; t < SEQ; ++t) {
        // ---- load embedding row of token t into slot t%3 (zero slots = padding) ----
        int tok  = xrow[t];
        int slot = t % 3;
        if (tid < 256) {
            float2 v = ((const float2*)(emb + (size_t)tok * EDIM))[tid];
            win[slot][2 * tid]     = v.x;
            win[slot][2 * tid + 1] = v.y;
        }

        // ---- q[e] = h@Wq col e ; gh (3 gate cols) = bh + h@Wh  (f16 dot2, f32 acc) ----
        float accq = 0.f, ghr = bh0, ghz = bh1, ghn = bh2;
        {
            const uint4* wq = Wq_p + tid;
            const uint4* wh = Wh_p + tid;
            #pragma unroll 4
            for (int m4 = 0; m4 < 64; ++m4) {
                uint4 hv  = h_pk4[m4];
                uint4 wqv = wq[m4 * 512];
                uint4 w0  = wh[m4 * 1536];
                uint4 w1  = wh[m4 * 1536 + 512];
                uint4 w2  = wh[m4 * 1536 + 1024];
                accq = fdot2u(hv.x, wqv.x, accq); accq = fdot2u(hv.y, wqv.y, accq);
                accq = fdot2u(hv.z, wqv.z, accq); accq = fdot2u(hv.w, wqv.w, accq);
                ghr  = fdot2u(hv.x, w0.x, ghr);   ghr  = fdot2u(hv.y, w0.y, ghr);
                ghr  = fdot2u(hv.z, w0.z, ghr);   ghr  = fdot2u(hv.w, w0.w, ghr);
                ghz  = fdot2u(hv.x, w1.x, ghz);   ghz  = fdot2u(hv.y, w1.y, ghz);
                ghz  = fdot2u(hv.z, w1.z, ghz);   ghz  = fdot2u(hv.w, w1.w, ghz);
                ghn  = fdot2u(hv.x, w2.x, ghn);   ghn  = fdot2u(hv.y, w2.y, ghn);
                ghn  = fdot2u(hv.z, w2.z, ghn);   ghn  = fdot2u(hv.w, w2.w, ghn);
            }
        }
        __syncthreads();   // win + (q in regs) ready

        // ---- attention: wave = head (64 dims = 64 lanes); window g -> row t-2+g ----
        {
            int s0 = (t + 1) % 3, s1 = (t + 2) % 3;   // rows t-2, t-1 ; slot = row t
            float k0 = win[s0][tid], k1 = win[s1][tid], k2 = win[slot][tid];
            float p0 = accq * k0, p1 = accq * k1, p2 = accq * k2;
            #pragma unroll
            for (int o = 32; o >= 1; o >>= 1) {
                p0 += __shfl_xor(p0, o);
                p1 += __shfl_xor(p1, o);
                p2 += __shfl_xor(p2, o);
            }
            p0 *= 0.125f; p1 *= 0.125f; p2 *= 0.125f;   // 1/sqrt(hd=64)
            float mx = fmaxf(p0, fmaxf(p1, p2));
            float e0 = __expf(p0 - mx), e1 = __expf(p1 - mx), e2 = __expf(p2 - mx);
            float inv  = 1.f / (e0 + e1 + e2);
            float ctxd = (e0 * k0 + e1 * k1 + e2 * k2) * inv;
            float cpart = __shfl_down(ctxd, 1);
            if ((lane & 1) == 0) c_pku[tid >> 1] = pack2f16(ctxd, cpart);
        }
        __syncthreads();   // ctx packed ready

        // ---- gx = bx + ctx@Wx (3 gate cols) ; GRU pointwise ; h update ----
        float gxr = bx0, gxz = bx1, gxn = bx2;
        {
            const uint4* wx = Wx_p + tid;
            #pragma unroll 4
            for (int m4 = 0; m4 < 64; ++m4) {
                uint4 cv = c_pk4[m4];
                uint4 w0 = wx[m4 * 1536];
                uint4 w1 = wx[m4 * 1536 + 512];
                uint4 w2 = wx[m4 * 1536 + 1024];
                gxr = fdot2u(cv.x, w0.x, gxr); gxr = fdot2u(cv.y, w0.y, gxr);
                gxr = fdot2u(cv.z, w0.z, gxr); gxr = fdot2u(cv.w, w0.w, gxr);
                gxz = fdot2u(cv.x, w1.x, gxz); gxz = fdot2u(cv.y, w1.y, gxz);
                gxz = fdot2u(cv.z, w1.z, gxz); gxz = fdot2u(cv.w, w1.w, gxz);
                gxn = fdot2u(cv.x, w2.x, gxn); gxn = fdot2u(cv.y, w2.y, gxn);
                gxn = fdot2u(cv.z, w2.z, gxn); gxn = fdot2u(cv.w, w2.w, gxn);
            }
        }
        float r = fsigmoid(gxr + ghr);
        float z = fsigmoid(gxz + ghz);
        float n = ftanhf(gxn + r * ghn);
        float hnew = (1.f - z) * n + z * hcur;
        hcur = hnew;
        pooled += hnew;
        float hpart = __shfl_down(hnew, 1);
        if ((lane & 1) == 0) h_pku[tid >> 1] = pack2f16(hnew, hpart);
        __syncthreads();   // h packed ready for next step
    }

    // ---- epilogue: relu(pooled) @ W1 + b1 -> @ W2 + b2 (f32) ----
    win[0][tid] = fmaxf(pooled, 0.f);
    __syncthreads();
    float o1 = b1[tid];
    for (int j = 0; j < 512; ++j) o1 += win[0][j] * W1[(size_t)j * 512 + tid];
    __syncthreads();
    win[1][tid] = o1;
    __syncthreads();
    if (tid < 10) {
        float o2 = b2[tid];
        for (int j = 0; j < 512; ++j) o2 += win[1][j] * W2[j * 10 + tid];
        out[b * 10 + tid] = o2;
    }
}

extern "C" void kernel_launch(void* const* d_in, const int* in_sizes, int n_in,
                              void* d_out, int out_size, void* d_ws, size_t ws_size,
                              hipStream_t stream) {
    const int*   x   = (const int*)d_in[0];
    const float* emb = (const float*)d_in[1];
    const float* Wq  = (const float*)d_in[2];
    const float* Wx  = (const float*)d_in[3];
    const float* Wh  = (const float*)d_in[4];
    const float* bx  = (const float*)d_in[5];
    const float* bh  = (const float*)d_in[6];
    const float* W1  = (const float*)d_in[7];
    const float* b1  = (const float*)d_in[8];
    const float* W2  = (const float*)d_in[9];
    const float* b2  = (const float*)d_in[10];
    uint4* wsp = (uint4*)d_ws;

    // 64*512 + 2*64*1536 = 229376 uint4 elements to pack (3.5 MB)
    hipLaunchKernelGGL(pack_weights, dim3(896), dim3(256), 0, stream, Wq, Wx, Wh, wsp);
    hipLaunchKernelGGL(gru_scan, dim3(NB), dim3(512), 0, stream,
                       x, emb, wsp, bx, bh, W1, b1, W2, b2, (float*)d_out);
}